// Round 1
// baseline (975.152 us; speedup 1.0000x reference)
//
#include <hip/hip_runtime.h>
#include <math.h>

#define EPSV 1.1920929e-07f

// ======================================================================
// GEMM: C[M,N] = A[M,K](row-major, row stride lda) @ B[K,N] + bias[N]
// Tiles 64(M) x 64(N) x 16(K), 256 threads, 4x4 microtile per thread.
// Requires M%64==0, N%64==0, K%16==0 (true for all calls here).
// ======================================================================
__global__ __launch_bounds__(256) void sgemm_bias(
    const float* __restrict__ A, int lda,
    const float* __restrict__ Bm,
    const float* __restrict__ bias,
    float* __restrict__ C,
    int M, int N, int K)
{
    __shared__ float As[16][68];   // [k][m], padded
    __shared__ float Bs[16][68];   // [k][n], padded
    const int t  = threadIdx.x;
    const int tx = t & 15, ty = t >> 4;
    const int m0 = blockIdx.y << 6;
    const int n0 = blockIdx.x << 6;

    float acc[4][4] = {{0.f}};

    const int arow = t >> 2;          // 0..63
    const int acol = (t & 3) << 2;    // 0,4,8,12
    const int brow = t >> 4;          // 0..15
    const int bcol = (t & 15) << 2;   // 0..60

    for (int k0 = 0; k0 < K; k0 += 16) {
        const float4 a4 = *(const float4*)&A[(size_t)(m0 + arow) * lda + k0 + acol];
        const float4 b4 = *(const float4*)&Bm[(size_t)(k0 + brow) * N + n0 + bcol];
        As[acol + 0][arow] = a4.x;
        As[acol + 1][arow] = a4.y;
        As[acol + 2][arow] = a4.z;
        As[acol + 3][arow] = a4.w;
        *(float4*)&Bs[brow][bcol] = b4;
        __syncthreads();
        #pragma unroll
        for (int k = 0; k < 16; ++k) {
            const float4 av = *(const float4*)&As[k][ty << 2];
            const float4 bv = *(const float4*)&Bs[k][tx << 2];
            const float aa[4] = {av.x, av.y, av.z, av.w};
            const float bb[4] = {bv.x, bv.y, bv.z, bv.w};
            #pragma unroll
            for (int i = 0; i < 4; ++i)
                #pragma unroll
                for (int j = 0; j < 4; ++j)
                    acc[i][j] = fmaf(aa[i], bb[j], acc[i][j]);
        }
        __syncthreads();
    }

    const float4 bv = *(const float4*)&bias[n0 + (tx << 2)];
    const float bb[4] = {bv.x, bv.y, bv.z, bv.w};
    #pragma unroll
    for (int i = 0; i < 4; ++i) {
        float4 o;
        o.x = acc[i][0] + bb[0];
        o.y = acc[i][1] + bb[1];
        o.z = acc[i][2] + bb[2];
        o.w = acc[i][3] + bb[3];
        *(float4*)&C[(size_t)(m0 + (ty << 2) + i) * N + n0 + (tx << 2)] = o;
    }
}

// ======================================================================
// RMSNorm (over D=64) then rotary, in-place on the q and k slices of
// qkv laid out (B*T, 3, 16, 64). One wave per (b,t,h,{q|k}) row.
// ======================================================================
__global__ __launch_bounds__(256) void rmsnorm_rope(
    float* __restrict__ qkv, const float* __restrict__ cosp,
    const float* __restrict__ sinp, int BT, int T)
{
    const int wid  = (blockIdx.x << 2) + (threadIdx.x >> 6);
    const int lane = threadIdx.x & 63;
    const int w  = wid & 1;           // 0 = q, 1 = k
    const int h  = (wid >> 1) & 15;
    const int bt = wid >> 5;
    if (bt >= BT) return;
    const int tpos = bt % T;
    const size_t idx = (size_t)bt * 3072 + (w << 10) + (h << 6) + lane;

    float x = qkv[idx];
    float ss = x * x;
    #pragma unroll
    for (int m = 1; m < 64; m <<= 1) ss += __shfl_xor(ss, m, 64);
    const float rn = rsqrtf(ss * (1.0f / 64.0f) + EPSV);
    const float xn = x * rn;
    const float other = __shfl_xor(xn, 32, 64);
    const float rot = (lane < 32) ? -other : other;
    const float c = cosp[tpos * 64 + lane];
    const float s = sinp[tpos * 64 + lane];
    qkv[idx] = fmaf(xn, c, rot * s);
}

// ======================================================================
// Flash attention, fp32. Block = one (b,h) and 32 Q rows. K/V tiles of
// 64 rows. Online softmax. Writes y (B,T,16,64) into ydst (row stride
// ldy) -- ydst may alias the q-slice of qkv (q fully consumed first).
// Thread layout: ty=t>>4 owns 2 rows (ty*2+i); tx=t&15.
//   S/P columns owned interleaved: s = j*16+tx  (2-way LDS conflicts max)
//   O columns owned blocked:       d = tx*4+j   (float4 stores)
// ======================================================================
__global__ __launch_bounds__(256) void flash_attn(
    const float* __restrict__ qkv, float* __restrict__ ydst, int ldy,
    int B, int T)
{
    const int b  = blockIdx.x >> 4;
    const int h  = blockIdx.x & 15;
    const int q0 = blockIdx.y << 5;
    const int t  = threadIdx.x;
    const int tx = t & 15;
    const int ty = t >> 4;

    __shared__ float Qs[32][68];
    __shared__ float Ks[64][68];
    __shared__ float Vs[64][68];
    __shared__ float Ps[32][68];

    const float* base = qkv + (size_t)b * T * 3072 + (h << 6);
    const float* qb = base;
    const float* kb = base + 1024;
    const float* vb = base + 2048;

    // ---- load Q tile (32 x 64): each thread 2 float4 ----
    {
        const int f   = t << 1;          // float4 id 0..511
        const int row = f >> 4;          // 0..31
        const int cb  = (f & 15) << 2;   // 0,8,...,56
        const float* src = &qb[(size_t)(q0 + row) * 3072 + cb];
        *(float4*)&Qs[row][cb]     = *(const float4*)&src[0];
        *(float4*)&Qs[row][cb + 4] = *(const float4*)&src[4];
    }

    float m_i[2] = {-INFINITY, -INFINITY};
    float l_i[2] = {0.f, 0.f};
    float o[2][4] = {{0.f}};

    const int kvrow = t >> 2;            // 0..63
    const int kvcb  = (t & 3) << 4;      // 0,16,32,48

    const int ktiles = ((q0 + 31) >> 6) + 1;
    for (int kt = 0; kt < ktiles; ++kt) {
        const int k0 = kt << 6;
        __syncthreads();   // prev PV reads done (and Q writes visible on kt==0)
        #pragma unroll
        for (int i = 0; i < 4; ++i) {
            *(float4*)&Ks[kvrow][kvcb + (i << 2)] =
                *(const float4*)&kb[(size_t)(k0 + kvrow) * 3072 + kvcb + (i << 2)];
            *(float4*)&Vs[kvrow][kvcb + (i << 2)] =
                *(const float4*)&vb[(size_t)(k0 + kvrow) * 3072 + kvcb + (i << 2)];
        }
        __syncthreads();

        // ---- S = Q K^T (rows ty*2+i, cols j*16+tx) ----
        float sacc[2][4] = {{0.f}};
        #pragma unroll
        for (int d4 = 0; d4 < 16; ++d4) {
            float4 q4[2], k4[4];
            #pragma unroll
            for (int i = 0; i < 2; ++i)
                q4[i] = *(const float4*)&Qs[(ty << 1) + i][d4 << 2];
            #pragma unroll
            for (int j = 0; j < 4; ++j)
                k4[j] = *(const float4*)&Ks[(j << 4) + tx][d4 << 2];
            #pragma unroll
            for (int i = 0; i < 2; ++i)
                #pragma unroll
                for (int j = 0; j < 4; ++j)
                    sacc[i][j] += q4[i].x * k4[j].x + q4[i].y * k4[j].y
                                + q4[i].z * k4[j].z + q4[i].w * k4[j].w;
        }

        // ---- scale, mask, online softmax ----
        const float scale = 0.125f;               // 1/sqrt(64)
        const bool need_mask = (k0 + 63 > q0);    // only last tile(s)
        #pragma unroll
        for (int i = 0; i < 2; ++i) {
            const int qrow = q0 + (ty << 1) + i;
            float p[4];
            #pragma unroll
            for (int j = 0; j < 4; ++j) {
                float v = sacc[i][j] * scale;
                if (need_mask && (k0 + (j << 4) + tx > qrow)) v = -INFINITY;
                p[j] = v;
            }
            float mx = fmaxf(fmaxf(p[0], p[1]), fmaxf(p[2], p[3]));
            #pragma unroll
            for (int m = 1; m < 16; m <<= 1) mx = fmaxf(mx, __shfl_xor(mx, m, 64));
            const float mnew  = fmaxf(m_i[i], mx);
            const float alpha = __expf(m_i[i] - mnew);
            float rs = 0.f;
            #pragma unroll
            for (int j = 0; j < 4; ++j) {
                p[j] = __expf(p[j] - mnew);
                rs += p[j];
            }
            #pragma unroll
            for (int m = 1; m < 16; m <<= 1) rs += __shfl_xor(rs, m, 64);
            l_i[i] = l_i[i] * alpha + rs;
            m_i[i] = mnew;
            #pragma unroll
            for (int j = 0; j < 4; ++j) o[i][j] *= alpha;
            #pragma unroll
            for (int j = 0; j < 4; ++j)
                Ps[(ty << 1) + i][(j << 4) + tx] = p[j];
        }
        __syncthreads();

        // ---- O += P V (O rows ty*2+i, cols tx*4+j) ----
        #pragma unroll
        for (int s4 = 0; s4 < 16; ++s4) {
            float4 p4[2], v4[4];
            #pragma unroll
            for (int i = 0; i < 2; ++i)
                p4[i] = *(const float4*)&Ps[(ty << 1) + i][s4 << 2];
            #pragma unroll
            for (int r = 0; r < 4; ++r)
                v4[r] = *(const float4*)&Vs[(s4 << 2) + r][tx << 2];
            #pragma unroll
            for (int i = 0; i < 2; ++i) {
                o[i][0] += p4[i].x * v4[0].x + p4[i].y * v4[1].x + p4[i].z * v4[2].x + p4[i].w * v4[3].x;
                o[i][1] += p4[i].x * v4[0].y + p4[i].y * v4[1].y + p4[i].z * v4[2].y + p4[i].w * v4[3].y;
                o[i][2] += p4[i].x * v4[0].z + p4[i].y * v4[1].z + p4[i].z * v4[2].z + p4[i].w * v4[3].z;
                o[i][3] += p4[i].x * v4[0].w + p4[i].y * v4[1].w + p4[i].z * v4[2].w + p4[i].w * v4[3].w;
            }
        }
    }

    // ---- epilogue: normalize and store ----
    #pragma unroll
    for (int i = 0; i < 2; ++i) {
        const float inv = 1.0f / l_i[i];
        const int tq = q0 + (ty << 1) + i;
        float4 ov;
        ov.x = o[i][0] * inv;
        ov.y = o[i][1] * inv;
        ov.z = o[i][2] * inv;
        ov.w = o[i][3] * inv;
        *(float4*)&ydst[((size_t)b * T + tq) * ldy + (h << 6) + (tx << 2)] = ov;
    }
}

// ======================================================================
extern "C" void kernel_launch(void* const* d_in, const int* in_sizes, int n_in,
                              void* d_out, int out_size, void* d_ws, size_t ws_size,
                              hipStream_t stream)
{
    const float* x      = (const float*)d_in[0];
    const float* cosp   = (const float*)d_in[1];
    const float* sinp   = (const float*)d_in[2];
    const float* W_attn = (const float*)d_in[3];
    const float* b_attn = (const float*)d_in[4];
    const float* W_proj = (const float*)d_in[5];
    const float* b_proj = (const float*)d_in[6];
    float* out = (float*)d_out;

    const int C = 1024, H = 16;
    const int T  = in_sizes[1] / 64;     // cos: (T, 64)
    const int BT = in_sizes[0] / C;      // B*T
    const int B  = BT / T;

    float* qkv = (float*)d_ws;           // BT x 3072 fp32 (48 MB)

    // 1) qkv = x @ W_attn + b_attn
    sgemm_bias<<<dim3(3 * C / 64, BT / 64), dim3(256), 0, stream>>>(
        x, C, W_attn, b_attn, qkv, BT, 3 * C, C);

    // 2) RMSNorm + rotary in-place on q and k slices
    rmsnorm_rope<<<dim3(BT * H * 2 / 4), dim3(256), 0, stream>>>(
        qkv, cosp, sinp, BT, T);

    // 3) attention; y written into the (dead after read) q-slice of qkv,
    //    i.e. y[bt][c] lives at qkv[bt*3072 + c]  (row stride 3072)
    flash_attn<<<dim3(B * H, T / 32), dim3(256), 0, stream>>>(
        qkv, qkv, 3072, B, T);

    // 4) out = y @ W_proj + b_proj   (A row stride 3072)
    sgemm_bias<<<dim3(C / 64, BT / 64), dim3(256), 0, stream>>>(
        qkv, 3072, W_proj, b_proj, out, BT, C, C);
}

// Round 2
// 609.949 us; speedup vs baseline: 1.5987x; 1.5987x over previous
//
#include <hip/hip_runtime.h>
#include <math.h>

#define EPSV 1.1920929e-07f

typedef __attribute__((ext_vector_type(8))) short short8;
typedef __attribute__((ext_vector_type(4))) float f32x4;

__device__ __forceinline__ float bf2f(unsigned short u) {
    union { unsigned int i; float f; } c; c.i = ((unsigned int)u) << 16; return c.f;
}
__device__ __forceinline__ unsigned short f2bf(float f) {
    union { float f; unsigned int i; } c; c.f = f;
    unsigned int r = c.i + 0x7FFFu + ((c.i >> 16) & 1u);   // RNE
    return (unsigned short)(r >> 16);
}

// ======================================================================
// cast fp32 -> bf16 elementwise (x). 4 elems/thread.
// ======================================================================
__global__ __launch_bounds__(256) void cast_bf16(
    const float* __restrict__ src, unsigned short* __restrict__ dst, int n)
{
    const int i = (blockIdx.x * 256 + threadIdx.x) * 4;
    if (i >= n) return;
    const float4 v = *(const float4*)&src[i];
    ushort4 o;
    o.x = f2bf(v.x); o.y = f2bf(v.y); o.z = f2bf(v.z); o.w = f2bf(v.w);
    *(ushort4*)&dst[i] = o;
}

// ======================================================================
// transpose + cast: W [K][N] fp32 -> Wt [N][K] bf16. 32x32 tiles.
// ======================================================================
__global__ __launch_bounds__(256) void transpose_cast(
    const float* __restrict__ W, unsigned short* __restrict__ Wt, int K, int N)
{
    __shared__ float tile[32][33];
    const int n0 = blockIdx.x * 32, k0 = blockIdx.y * 32;
    const int r = threadIdx.x >> 3, c4 = (threadIdx.x & 7) * 4;
    const float4 v = *(const float4*)&W[(size_t)(k0 + r) * N + n0 + c4];
    tile[r][c4 + 0] = v.x; tile[r][c4 + 1] = v.y;
    tile[r][c4 + 2] = v.z; tile[r][c4 + 3] = v.w;
    __syncthreads();
    ushort4 o;
    o.x = f2bf(tile[c4 + 0][r]); o.y = f2bf(tile[c4 + 1][r]);
    o.z = f2bf(tile[c4 + 2][r]); o.w = f2bf(tile[c4 + 3][r]);
    *(ushort4*)&Wt[(size_t)(n0 + r) * K + k0 + c4] = o;
}

// ======================================================================
// bf16 MFMA GEMM: C[M,N] = A[M,K] @ Bt[N,K]^T + bias[N]
// A, Bt bf16 row-major contiguous (lda = ldb = K). 128x128x32 tile,
// 256 thr = 4 waves in 2x2; each wave 64x64 = 4x4 MFMA 16x16x32 tiles.
// LDS rows padded to 40 shorts (80 B = 20 banks: 2-way max, 16B-aligned).
// ======================================================================
template <bool OUT_BF16>
__global__ __launch_bounds__(256) void gemm_bf16(
    const unsigned short* __restrict__ A,
    const unsigned short* __restrict__ Bt,
    const float* __restrict__ bias,
    void* __restrict__ Cv,
    int M, int N, int K)
{
    __shared__ unsigned short As[128][40];
    __shared__ unsigned short Bs[128][40];
    const int t    = threadIdx.x;
    const int lane = t & 63;
    const int wv   = t >> 6;
    const int wrow = (wv >> 1) * 64;
    const int wcol = (wv & 1) * 64;
    const int m0 = blockIdx.y * 128;
    const int n0 = blockIdx.x * 128;
    const int col  = lane & 15;
    const int quad = lane >> 4;

    f32x4 acc[4][4];
    #pragma unroll
    for (int i = 0; i < 4; ++i)
        #pragma unroll
        for (int j = 0; j < 4; ++j)
            acc[i][j] = (f32x4){0.f, 0.f, 0.f, 0.f};

    for (int k0 = 0; k0 < K; k0 += 32) {
        #pragma unroll
        for (int i = 0; i < 2; ++i) {
            const int s = t + (i << 8);
            const int r = s >> 2, q = (s & 3) << 3;      // q: 0,8,16,24 bf16
            *(short8*)&As[r][q] = *(const short8*)&A [(size_t)(m0 + r) * K + k0 + q];
            *(short8*)&Bs[r][q] = *(const short8*)&Bt[(size_t)(n0 + r) * K + k0 + q];
        }
        __syncthreads();
        short8 af[4], bf[4];
        #pragma unroll
        for (int mt = 0; mt < 4; ++mt)
            af[mt] = *(const short8*)&As[wrow + mt * 16 + col][quad << 3];
        #pragma unroll
        for (int nt = 0; nt < 4; ++nt)
            bf[nt] = *(const short8*)&Bs[wcol + nt * 16 + col][quad << 3];
        #pragma unroll
        for (int mt = 0; mt < 4; ++mt)
            #pragma unroll
            for (int nt = 0; nt < 4; ++nt)
                acc[mt][nt] = __builtin_amdgcn_mfma_f32_16x16x32_bf16(
                    af[mt], bf[nt], acc[mt][nt], 0, 0, 0);
        __syncthreads();
    }

    const int rowq = quad << 2;
    #pragma unroll
    for (int nt = 0; nt < 4; ++nt) {
        const int n = n0 + wcol + nt * 16 + col;
        const float bv = bias[n];
        #pragma unroll
        for (int mt = 0; mt < 4; ++mt) {
            #pragma unroll
            for (int r = 0; r < 4; ++r) {
                const int m = m0 + wrow + mt * 16 + rowq + r;
                const float v = acc[mt][nt][r] + bv;
                if (OUT_BF16)
                    ((unsigned short*)Cv)[(size_t)m * N + n] = f2bf(v);
                else
                    ((float*)Cv)[(size_t)m * N + n] = v;
            }
        }
    }
}

// ======================================================================
// RMSNorm (D=64) then rotary, in-place on bf16 q/k slices of
// qkv (B*T, 3, 16, 64). One wave per row; fp32 math.
// ======================================================================
__global__ __launch_bounds__(256) void rmsnorm_rope(
    unsigned short* __restrict__ qkv, const float* __restrict__ cosp,
    const float* __restrict__ sinp, int BT, int T)
{
    const int wid  = (blockIdx.x << 2) + (threadIdx.x >> 6);
    const int lane = threadIdx.x & 63;
    const int w  = wid & 1;
    const int h  = (wid >> 1) & 15;
    const int bt = wid >> 5;
    if (bt >= BT) return;
    const int tpos = bt % T;
    const size_t idx = (size_t)bt * 3072 + (w << 10) + (h << 6) + lane;

    const float x = bf2f(qkv[idx]);
    float ss = x * x;
    #pragma unroll
    for (int m = 1; m < 64; m <<= 1) ss += __shfl_xor(ss, m, 64);
    const float rn = rsqrtf(ss * (1.0f / 64.0f) + EPSV);
    const float xn = x * rn;
    const float other = __shfl_xor(xn, 32, 64);
    const float rot = (lane < 32) ? -other : other;
    const float c = cosp[tpos * 64 + lane];
    const float s = sinp[tpos * 64 + lane];
    qkv[idx] = f2bf(fmaf(xn, c, rot * s));
}

// ======================================================================
// Flash attention, fp32 compute, bf16 in/out. Block = (b,h,32 Q rows).
// ======================================================================
__global__ __launch_bounds__(256) void flash_attn(
    const unsigned short* __restrict__ qkv, unsigned short* __restrict__ ydst,
    int B, int T)
{
    const int b  = blockIdx.x >> 4;
    const int h  = blockIdx.x & 15;
    const int q0 = blockIdx.y << 5;
    const int t  = threadIdx.x;
    const int tx = t & 15;
    const int ty = t >> 4;

    __shared__ float Qs[32][68];
    __shared__ float Ks[64][68];
    __shared__ float Vs[64][68];
    __shared__ float Ps[32][68];

    const unsigned short* base = qkv + (size_t)b * T * 3072 + (h << 6);
    const unsigned short* qb = base;
    const unsigned short* kb = base + 1024;
    const unsigned short* vb = base + 2048;

    // ---- load Q tile (32 x 64 bf16 -> fp32) ----
    {
        const int row = t >> 3, c8 = (t & 7) << 3;
        const short8 v = *(const short8*)&qb[(size_t)(q0 + row) * 3072 + c8];
        #pragma unroll
        for (int j = 0; j < 8; ++j)
            Qs[row][c8 + j] = bf2f((unsigned short)v[j]);
    }

    float m_i[2] = {-INFINITY, -INFINITY};
    float l_i[2] = {0.f, 0.f};
    float o[2][4] = {{0.f}};

    const int kvrow = t >> 2;
    const int kvc   = (t & 3) << 4;

    const int ktiles = ((q0 + 31) >> 6) + 1;
    for (int kt = 0; kt < ktiles; ++kt) {
        const int k0 = kt << 6;
        __syncthreads();
        #pragma unroll
        for (int seg = 0; seg < 2; ++seg) {
            const short8 kv = *(const short8*)&kb[(size_t)(k0 + kvrow) * 3072 + kvc + (seg << 3)];
            const short8 vv = *(const short8*)&vb[(size_t)(k0 + kvrow) * 3072 + kvc + (seg << 3)];
            #pragma unroll
            for (int j = 0; j < 8; ++j) {
                Ks[kvrow][kvc + (seg << 3) + j] = bf2f((unsigned short)kv[j]);
                Vs[kvrow][kvc + (seg << 3) + j] = bf2f((unsigned short)vv[j]);
            }
        }
        __syncthreads();

        // ---- S = Q K^T ----
        float sacc[2][4] = {{0.f}};
        #pragma unroll
        for (int d4 = 0; d4 < 16; ++d4) {
            float4 q4[2], k4[4];
            #pragma unroll
            for (int i = 0; i < 2; ++i)
                q4[i] = *(const float4*)&Qs[(ty << 1) + i][d4 << 2];
            #pragma unroll
            for (int j = 0; j < 4; ++j)
                k4[j] = *(const float4*)&Ks[(j << 4) + tx][d4 << 2];
            #pragma unroll
            for (int i = 0; i < 2; ++i)
                #pragma unroll
                for (int j = 0; j < 4; ++j)
                    sacc[i][j] += q4[i].x * k4[j].x + q4[i].y * k4[j].y
                                + q4[i].z * k4[j].z + q4[i].w * k4[j].w;
        }

        // ---- scale, mask, online softmax ----
        const float scale = 0.125f;
        const bool need_mask = (k0 + 63 > q0);
        #pragma unroll
        for (int i = 0; i < 2; ++i) {
            const int qrow = q0 + (ty << 1) + i;
            float p[4];
            #pragma unroll
            for (int j = 0; j < 4; ++j) {
                float v = sacc[i][j] * scale;
                if (need_mask && (k0 + (j << 4) + tx > qrow)) v = -INFINITY;
                p[j] = v;
            }
            float mx = fmaxf(fmaxf(p[0], p[1]), fmaxf(p[2], p[3]));
            #pragma unroll
            for (int m = 1; m < 16; m <<= 1) mx = fmaxf(mx, __shfl_xor(mx, m, 64));
            const float mnew  = fmaxf(m_i[i], mx);
            const float alpha = __expf(m_i[i] - mnew);
            float rs = 0.f;
            #pragma unroll
            for (int j = 0; j < 4; ++j) {
                p[j] = __expf(p[j] - mnew);
                rs += p[j];
            }
            #pragma unroll
            for (int m = 1; m < 16; m <<= 1) rs += __shfl_xor(rs, m, 64);
            l_i[i] = l_i[i] * alpha + rs;
            m_i[i] = mnew;
            #pragma unroll
            for (int j = 0; j < 4; ++j) o[i][j] *= alpha;
            #pragma unroll
            for (int j = 0; j < 4; ++j)
                Ps[(ty << 1) + i][(j << 4) + tx] = p[j];
        }
        __syncthreads();

        // ---- O += P V ----
        #pragma unroll
        for (int s4 = 0; s4 < 16; ++s4) {
            float4 p4[2], v4[4];
            #pragma unroll
            for (int i = 0; i < 2; ++i)
                p4[i] = *(const float4*)&Ps[(ty << 1) + i][s4 << 2];
            #pragma unroll
            for (int r = 0; r < 4; ++r)
                v4[r] = *(const float4*)&Vs[(s4 << 2) + r][tx << 2];
            #pragma unroll
            for (int i = 0; i < 2; ++i) {
                o[i][0] += p4[i].x * v4[0].x + p4[i].y * v4[1].x + p4[i].z * v4[2].x + p4[i].w * v4[3].x;
                o[i][1] += p4[i].x * v4[0].y + p4[i].y * v4[1].y + p4[i].z * v4[2].y + p4[i].w * v4[3].y;
                o[i][2] += p4[i].x * v4[0].z + p4[i].y * v4[1].z + p4[i].z * v4[2].z + p4[i].w * v4[3].z;
                o[i][3] += p4[i].x * v4[0].w + p4[i].y * v4[1].w + p4[i].z * v4[2].w + p4[i].w * v4[3].w;
            }
        }
    }

    // ---- epilogue: normalize, cast, store bf16 ----
    #pragma unroll
    for (int i = 0; i < 2; ++i) {
        const float inv = 1.0f / l_i[i];
        const int tq = q0 + (ty << 1) + i;
        ushort4 ov;
        ov.x = f2bf(o[i][0] * inv);
        ov.y = f2bf(o[i][1] * inv);
        ov.z = f2bf(o[i][2] * inv);
        ov.w = f2bf(o[i][3] * inv);
        *(ushort4*)&ydst[((size_t)b * T + tq) * 1024 + (h << 6) + (tx << 2)] = ov;
    }
}

// ======================================================================
extern "C" void kernel_launch(void* const* d_in, const int* in_sizes, int n_in,
                              void* d_out, int out_size, void* d_ws, size_t ws_size,
                              hipStream_t stream)
{
    const float* x      = (const float*)d_in[0];
    const float* cosp   = (const float*)d_in[1];
    const float* sinp   = (const float*)d_in[2];
    const float* W_attn = (const float*)d_in[3];
    const float* b_attn = (const float*)d_in[4];
    const float* W_proj = (const float*)d_in[5];
    const float* b_proj = (const float*)d_in[6];
    float* out = (float*)d_out;

    const int C = 1024, H = 16;
    const int T  = in_sizes[1] / 64;     // cos: (T, 64)
    const int BT = in_sizes[0] / C;      // B*T
    const int B  = BT / T;

    // workspace layout (bf16), total 48 MiB for BT=4096:
    unsigned short* qkvb = (unsigned short*)d_ws;              // BT*3072
    unsigned short* xb   = qkvb + (size_t)BT * 3072;           // BT*1024
    unsigned short* Wab  = xb   + (size_t)BT * 1024;           // 3072*1024 (W_attn^T)
    unsigned short* Wpb  = Wab  + (size_t)3072 * 1024;         // 1024*1024 (W_proj^T)
    unsigned short* yb   = Wpb  + (size_t)1024 * 1024;         // BT*1024

    // 0) casts
    cast_bf16<<<dim3(BT * C / 1024), dim3(256), 0, stream>>>(x, xb, BT * C);
    transpose_cast<<<dim3(3 * C / 32, C / 32), dim3(256), 0, stream>>>(W_attn, Wab, C, 3 * C);
    transpose_cast<<<dim3(C / 32, C / 32), dim3(256), 0, stream>>>(W_proj, Wpb, C, C);

    // 1) qkv = x @ W_attn + b_attn   (bf16 MFMA, bf16 out)
    gemm_bf16<true><<<dim3(3 * C / 128, BT / 128), dim3(256), 0, stream>>>(
        xb, Wab, b_attn, qkvb, BT, 3 * C, C);

    // 2) RMSNorm + rotary in-place on q/k slices
    rmsnorm_rope<<<dim3(BT * H * 2 / 4), dim3(256), 0, stream>>>(
        qkvb, cosp, sinp, BT, T);

    // 3) attention -> yb (bf16)
    flash_attn<<<dim3(B * H, T / 32), dim3(256), 0, stream>>>(
        qkvb, yb, B, T);

    // 4) out = y @ W_proj + b_proj   (bf16 MFMA, fp32 out)
    gemm_bf16<false><<<dim3(C / 128, BT / 128), dim3(256), 0, stream>>>(
        yb, Wpb, b_proj, out, BT, C, C);
}

// Round 3
// 224.615 us; speedup vs baseline: 4.3414x; 2.7155x over previous
//
#include <hip/hip_runtime.h>
#include <math.h>

#define EPSV 1.1920929e-07f

typedef __attribute__((ext_vector_type(8))) short short8;
typedef __attribute__((ext_vector_type(4))) float f32x4;

__device__ __forceinline__ float bf2f(unsigned short u) {
    union { unsigned int i; float f; } c; c.i = ((unsigned int)u) << 16; return c.f;
}
__device__ __forceinline__ unsigned short f2bf(float f) {
    union { float f; unsigned int i; } c; c.f = f;
    unsigned int r = c.i + 0x7FFFu + ((c.i >> 16) & 1u);   // RNE
    return (unsigned short)(r >> 16);
}

// ======================================================================
// cast fp32 -> bf16 elementwise. 4 elems/thread.
// ======================================================================
__global__ __launch_bounds__(256) void cast_bf16(
    const float* __restrict__ src, unsigned short* __restrict__ dst, int n)
{
    const int i = (blockIdx.x * 256 + threadIdx.x) * 4;
    if (i >= n) return;
    const float4 v = *(const float4*)&src[i];
    ushort4 o;
    o.x = f2bf(v.x); o.y = f2bf(v.y); o.z = f2bf(v.z); o.w = f2bf(v.w);
    *(ushort4*)&dst[i] = o;
}

// ======================================================================
// transpose + cast: W [K][N] fp32 -> Wt [N][K] bf16. 32x32 tiles.
// ======================================================================
__global__ __launch_bounds__(256) void transpose_cast(
    const float* __restrict__ W, unsigned short* __restrict__ Wt, int K, int N)
{
    __shared__ float tile[32][33];
    const int n0 = blockIdx.x * 32, k0 = blockIdx.y * 32;
    const int r = threadIdx.x >> 3, c4 = (threadIdx.x & 7) * 4;
    const float4 v = *(const float4*)&W[(size_t)(k0 + r) * N + n0 + c4];
    tile[r][c4 + 0] = v.x; tile[r][c4 + 1] = v.y;
    tile[r][c4 + 2] = v.z; tile[r][c4 + 3] = v.w;
    __syncthreads();
    ushort4 o;
    o.x = f2bf(tile[c4 + 0][r]); o.y = f2bf(tile[c4 + 1][r]);
    o.z = f2bf(tile[c4 + 2][r]); o.w = f2bf(tile[c4 + 3][r]);
    *(ushort4*)&Wt[(size_t)(n0 + r) * K + k0 + c4] = o;
}

// ======================================================================
// bf16 MFMA GEMM: C[M,N] = A[M,K] @ Bt[N,K]^T + bias[N]
// 128x128x32 tile, 4 waves 2x2, 4x4 MFMA 16x16x32 per wave.
// ======================================================================
template <bool OUT_BF16>
__global__ __launch_bounds__(256) void gemm_bf16(
    const unsigned short* __restrict__ A,
    const unsigned short* __restrict__ Bt,
    const float* __restrict__ bias,
    void* __restrict__ Cv,
    int M, int N, int K)
{
    __shared__ unsigned short As[128][40];
    __shared__ unsigned short Bs[128][40];
    const int t    = threadIdx.x;
    const int lane = t & 63;
    const int wv   = t >> 6;
    const int wrow = (wv >> 1) * 64;
    const int wcol = (wv & 1) * 64;
    const int m0 = blockIdx.y * 128;
    const int n0 = blockIdx.x * 128;
    const int col  = lane & 15;
    const int quad = lane >> 4;

    f32x4 acc[4][4];
    #pragma unroll
    for (int i = 0; i < 4; ++i)
        #pragma unroll
        for (int j = 0; j < 4; ++j)
            acc[i][j] = (f32x4){0.f, 0.f, 0.f, 0.f};

    for (int k0 = 0; k0 < K; k0 += 32) {
        #pragma unroll
        for (int i = 0; i < 2; ++i) {
            const int s = t + (i << 8);
            const int r = s >> 2, q = (s & 3) << 3;
            *(short8*)&As[r][q] = *(const short8*)&A [(size_t)(m0 + r) * K + k0 + q];
            *(short8*)&Bs[r][q] = *(const short8*)&Bt[(size_t)(n0 + r) * K + k0 + q];
        }
        __syncthreads();
        short8 af[4], bf[4];
        #pragma unroll
        for (int mt = 0; mt < 4; ++mt)
            af[mt] = *(const short8*)&As[wrow + mt * 16 + col][quad << 3];
        #pragma unroll
        for (int nt = 0; nt < 4; ++nt)
            bf[nt] = *(const short8*)&Bs[wcol + nt * 16 + col][quad << 3];
        #pragma unroll
        for (int mt = 0; mt < 4; ++mt)
            #pragma unroll
            for (int nt = 0; nt < 4; ++nt)
                acc[mt][nt] = __builtin_amdgcn_mfma_f32_16x16x32_bf16(
                    af[mt], bf[nt], acc[mt][nt], 0, 0, 0);
        __syncthreads();
    }

    const int rowq = quad << 2;
    #pragma unroll
    for (int nt = 0; nt < 4; ++nt) {
        const int n = n0 + wcol + nt * 16 + col;
        const float bv = bias[n];
        #pragma unroll
        for (int mt = 0; mt < 4; ++mt) {
            #pragma unroll
            for (int r = 0; r < 4; ++r) {
                const int m = m0 + wrow + mt * 16 + rowq + r;
                const float v = acc[mt][nt][r] + bv;
                if (OUT_BF16)
                    ((unsigned short*)Cv)[(size_t)m * N + n] = f2bf(v);
                else
                    ((float*)Cv)[(size_t)m * N + n] = v;
            }
        }
    }
}

// ======================================================================
// RMSNorm (D=64) then rotary, in-place on bf16 q/k slices.
// ======================================================================
__global__ __launch_bounds__(256) void rmsnorm_rope(
    unsigned short* __restrict__ qkv, const float* __restrict__ cosp,
    const float* __restrict__ sinp, int BT, int T)
{
    const int wid  = (blockIdx.x << 2) + (threadIdx.x >> 6);
    const int lane = threadIdx.x & 63;
    const int w  = wid & 1;
    const int h  = (wid >> 1) & 15;
    const int bt = wid >> 5;
    if (bt >= BT) return;
    const int tpos = bt % T;
    const size_t idx = (size_t)bt * 3072 + (w << 10) + (h << 6) + lane;

    const float x = bf2f(qkv[idx]);
    float ss = x * x;
    #pragma unroll
    for (int m = 1; m < 64; m <<= 1) ss += __shfl_xor(ss, m, 64);
    const float rn = rsqrtf(ss * (1.0f / 64.0f) + EPSV);
    const float xn = x * rn;
    const float other = __shfl_xor(xn, 32, 64);
    const float rot = (lane < 32) ? -other : other;
    const float c = cosp[tpos * 64 + lane];
    const float s = sinp[tpos * 64 + lane];
    qkv[idx] = f2bf(fmaf(xn, c, rot * s));
}

// ======================================================================
// V transpose: qkv v-slice [b,t,h,d] -> vt [b,h,d,t]. 64x64 tiles.
// ======================================================================
__global__ __launch_bounds__(256) void v_transpose(
    const unsigned short* __restrict__ qkv, unsigned short* __restrict__ vt,
    int T)
{
    __shared__ unsigned short tile[64][72];
    const int bh = blockIdx.x;
    const int b  = bh >> 4, h = bh & 15;
    const int t0 = blockIdx.y << 6;
    const int t  = threadIdx.x;
    const unsigned short* vbase = qkv + (size_t)b * T * 3072 + 2048 + (h << 6);

    #pragma unroll
    for (int i = 0; i < 2; ++i) {
        const int c = t + (i << 8);
        const int r = c >> 3, c8 = (c & 7) << 3;   // r: t-row, c8: d chunk
        const short8 v = *(const short8*)&vbase[(size_t)(t0 + r) * 3072 + c8];
        #pragma unroll
        for (int j = 0; j < 8; ++j)
            tile[c8 + j][r] = (unsigned short)v[j];
    }
    __syncthreads();
    #pragma unroll
    for (int i = 0; i < 2; ++i) {
        const int c = t + (i << 8);
        const int d = c >> 3, c8 = (c & 7) << 3;   // c8: t chunk
        const short8 o = *(const short8*)&tile[d][c8];
        *(short8*)&vt[((size_t)bh * 64 + d) * T + t0 + c8] = o;
    }
}

// ======================================================================
// MFMA flash attention (bf16 inputs, fp32 softmax/accum, bf16 out).
// Block = (b,h) x 64 q-rows; 4 waves, wave w owns q-rows q0+w*16..+15.
// Computes S^T = K @ Q^T so softmax state is per-lane (col = q);
// PV as O^T = V^T @ P^T (V^T from pre-transposed vt buffer).
// All LDS rows padded to 72 shorts (36 words -> minimum-phase banks).
// ======================================================================
__global__ __launch_bounds__(256) void flash_attn_mfma(
    const unsigned short* __restrict__ qkv,
    const unsigned short* __restrict__ vt,
    unsigned short* __restrict__ yb,
    int B, int T)
{
    const int bh = blockIdx.x;
    const int b  = bh >> 4, h = bh & 15;
    const int q0 = ((int)gridDim.y - 1 - (int)blockIdx.y) << 6;  // heavy blocks first
    const int t  = threadIdx.x;
    const int lane = t & 63;
    const int w    = t >> 6;
    const int col  = lane & 15;
    const int quad = lane >> 4;

    __shared__ unsigned short Ks [64][72];
    __shared__ unsigned short Vts[64][72];
    __shared__ unsigned short Ps [4][16][72];

    const unsigned short* qb  = qkv + (size_t)b * T * 3072 + (h << 6);
    const unsigned short* kb  = qb + 1024;
    const unsigned short* vtb = vt + (size_t)bh * 64 * T;

    // ---- Q B-frags (x 1/8 scale folded in; exact in bf16) ----
    const int qg = q0 + w * 16 + col;          // this lane's q row
    short8 qf[2];
    {
        const unsigned short* qrow = qb + (size_t)qg * 3072;
        #pragma unroll
        for (int ks = 0; ks < 2; ++ks) {
            short8 v = *(const short8*)&qrow[ks * 32 + (quad << 3)];
            #pragma unroll
            for (int j = 0; j < 8; ++j)
                v[j] = (short)f2bf(bf2f((unsigned short)v[j]) * 0.125f);
            qf[ks] = v;
        }
    }

    f32x4 oacc[4];
    #pragma unroll
    for (int i = 0; i < 4; ++i) oacc[i] = (f32x4){0.f, 0.f, 0.f, 0.f};
    float m_i = -INFINITY, l_i = 0.f;

    const int last_kt = q0 >> 6;
    for (int kt = 0; kt <= last_kt; ++kt) {
        const int k0 = kt << 6;
        __syncthreads();
        // ---- stage K tile and V^T tile ----
        #pragma unroll
        for (int i = 0; i < 2; ++i) {
            const int c = t + (i << 8);
            const int r = c >> 3, c8 = (c & 7) << 3;
            *(short8*)&Ks [r][c8] = *(const short8*)&kb [(size_t)(k0 + r) * 3072 + c8];
            *(short8*)&Vts[r][c8] = *(const short8*)&vtb[(size_t)r * T + k0 + c8];
        }
        __syncthreads();

        // ---- S^T = K @ Q^T : 4 s-tiles x 2 d-steps ----
        f32x4 st[4];
        #pragma unroll
        for (int i = 0; i < 4; ++i) st[i] = (f32x4){0.f, 0.f, 0.f, 0.f};
        #pragma unroll
        for (int ks = 0; ks < 2; ++ks)
            #pragma unroll
            for (int mt = 0; mt < 4; ++mt) {
                const short8 kf = *(const short8*)&Ks[mt * 16 + col][ks * 32 + (quad << 3)];
                st[mt] = __builtin_amdgcn_mfma_f32_16x16x32_bf16(kf, qf[ks], st[mt], 0, 0, 0);
            }

        // ---- online softmax (per-lane state; col = q) ----
        const bool need_mask = (kt == last_kt);
        float sv[4][4];
        float mloc = -INFINITY;
        #pragma unroll
        for (int mt = 0; mt < 4; ++mt) {
            const int sbase = k0 + mt * 16 + (quad << 2);
            #pragma unroll
            for (int r = 0; r < 4; ++r) {
                float x = st[mt][r];
                if (need_mask && (sbase + r > qg)) x = -INFINITY;
                sv[mt][r] = x;
                mloc = fmaxf(mloc, x);
            }
        }
        mloc = fmaxf(mloc, __shfl_xor(mloc, 16, 64));
        mloc = fmaxf(mloc, __shfl_xor(mloc, 32, 64));
        const float mnew  = fmaxf(m_i, mloc);
        const float alpha = __expf(m_i - mnew);
        float rs = 0.f;
        #pragma unroll
        for (int mt = 0; mt < 4; ++mt) {
            ushort4 pk;
            float p0 = __expf(sv[mt][0] - mnew);
            float p1 = __expf(sv[mt][1] - mnew);
            float p2 = __expf(sv[mt][2] - mnew);
            float p3 = __expf(sv[mt][3] - mnew);
            rs += (p0 + p1) + (p2 + p3);
            pk.x = f2bf(p0); pk.y = f2bf(p1); pk.z = f2bf(p2); pk.w = f2bf(p3);
            *(ushort4*)&Ps[w][col][mt * 16 + (quad << 2)] = pk;
        }
        rs += __shfl_xor(rs, 16, 64);
        rs += __shfl_xor(rs, 32, 64);
        l_i = l_i * alpha + rs;
        m_i = mnew;
        #pragma unroll
        for (int mt = 0; mt < 4; ++mt) {
            oacc[mt][0] *= alpha; oacc[mt][1] *= alpha;
            oacc[mt][2] *= alpha; oacc[mt][3] *= alpha;
        }

        // ---- O^T += V^T @ P^T ----
        #pragma unroll
        for (int ks = 0; ks < 2; ++ks) {
            const short8 pf = *(const short8*)&Ps[w][col][ks * 32 + (quad << 3)];
            #pragma unroll
            for (int mt = 0; mt < 4; ++mt) {
                const short8 vf = *(const short8*)&Vts[mt * 16 + col][ks * 32 + (quad << 3)];
                oacc[mt] = __builtin_amdgcn_mfma_f32_16x16x32_bf16(vf, pf, oacc[mt], 0, 0, 0);
            }
        }
    }

    // ---- epilogue: normalize, store y[b,t,h,d] (bf16) ----
    const float inv = 1.0f / l_i;
    unsigned short* yrow = yb + (size_t)(b * T + qg) * 1024 + (h << 6);
    #pragma unroll
    for (int mt = 0; mt < 4; ++mt) {
        ushort4 yv;
        yv.x = f2bf(oacc[mt][0] * inv);
        yv.y = f2bf(oacc[mt][1] * inv);
        yv.z = f2bf(oacc[mt][2] * inv);
        yv.w = f2bf(oacc[mt][3] * inv);
        *(ushort4*)&yrow[mt * 16 + (quad << 2)] = yv;
    }
}

// ======================================================================
extern "C" void kernel_launch(void* const* d_in, const int* in_sizes, int n_in,
                              void* d_out, int out_size, void* d_ws, size_t ws_size,
                              hipStream_t stream)
{
    const float* x      = (const float*)d_in[0];
    const float* cosp   = (const float*)d_in[1];
    const float* sinp   = (const float*)d_in[2];
    const float* W_attn = (const float*)d_in[3];
    const float* b_attn = (const float*)d_in[4];
    const float* W_proj = (const float*)d_in[5];
    const float* b_proj = (const float*)d_in[6];
    float* out = (float*)d_out;

    const int C = 1024, H = 16;
    const int T  = in_sizes[1] / 64;     // cos: (T, 64)
    const int BT = in_sizes[0] / C;      // B*T
    const int B  = BT / T;

    // workspace (bf16), 50.3 MB total for BT=4096 (same as round-1 cap):
    unsigned short* qkvb = (unsigned short*)d_ws;              // BT*3072
    unsigned short* xb   = qkvb + (size_t)BT * 3072;           // BT*1024
    unsigned short* Wab  = xb   + (size_t)BT * 1024;           // 3072*1024
    unsigned short* Wpb  = Wab  + (size_t)3072 * 1024;         // 1024*1024
    unsigned short* yb   = Wpb  + (size_t)1024 * 1024;         // BT*1024
    unsigned short* vtb  = xb;   // vt aliases xb (x dead after gemm1)

    cast_bf16<<<dim3(BT * C / 1024), dim3(256), 0, stream>>>(x, xb, BT * C);
    transpose_cast<<<dim3(3 * C / 32, C / 32), dim3(256), 0, stream>>>(W_attn, Wab, C, 3 * C);
    transpose_cast<<<dim3(C / 32, C / 32), dim3(256), 0, stream>>>(W_proj, Wpb, C, C);

    gemm_bf16<true><<<dim3(3 * C / 128, BT / 128), dim3(256), 0, stream>>>(
        xb, Wab, b_attn, qkvb, BT, 3 * C, C);

    rmsnorm_rope<<<dim3(BT * H * 2 / 4), dim3(256), 0, stream>>>(
        qkvb, cosp, sinp, BT, T);

    v_transpose<<<dim3(B * H, T / 64), dim3(256), 0, stream>>>(qkvb, vtb, T);

    flash_attn_mfma<<<dim3(B * H, T / 64), dim3(256), 0, stream>>>(
        qkvb, vtb, yb, B, T);

    gemm_bf16<false><<<dim3(C / 128, BT / 128), dim3(256), 0, stream>>>(
        yb, Wpb, b_proj, out, BT, C, C);
}